// Round 2
// baseline (130.275 us; speedup 1.0000x reference)
//
#include <hip/hip_runtime.h>
#include <math.h>

#define GRID_D 362
#define NKEYS  10000
#define EPSV   1e-8f
#define MROWS  8

// ---------------- prep: per-row argmax/query/cells + bucket by a ----------------
__global__ __launch_bounds__(64) void prep_kernel(
    const float* __restrict__ batch_x,   // [B, 362]
    const int*   __restrict__ batch_a,   // [B]
    int*   __restrict__ cnt,             // [4]  (zeroed before launch)
    int*   __restrict__ rowlist,         // [3*B]
    float* __restrict__ qout,            // [B*6]
    int*   __restrict__ cellout,         // [B*6]
    int B)
{
    const int b    = blockIdx.x;
    const int lane = threadIdx.x;
    const float* x = batch_x + (size_t)b * GRID_D;

    float bestv = -INFINITY;
    int   besti = 1 << 30;
    for (int i = lane; i < GRID_D; i += 64) {
        float v = x[i];
        if (v > bestv || (v == bestv && i < besti)) { bestv = v; besti = i; }
    }
#pragma unroll
    for (int off = 32; off > 0; off >>= 1) {
        float ov = __shfl_down(bestv, off);
        int   oi = __shfl_down(besti, off);
        if (ov > bestv || (ov == bestv && oi < besti)) { bestv = ov; besti = oi; }
    }
    if (lane == 0) {
        const int ptr = besti;
        int cells[6];
        cells[0] = 0;
        cells[1] = ptr;
        cells[2] = min(max(ptr - 19, 1), GRID_D - 1);
        cells[3] = min(max(ptr + 19, 1), GRID_D - 1);
        cells[4] = min(max(ptr - 1,  1), GRID_D - 1);
        cells[5] = min(max(ptr + 1,  1), GRID_D - 1);
        float att[6], ss = 0.f;
#pragma unroll
        for (int j = 0; j < 6; ++j) { att[j] = x[cells[j]]; ss += att[j] * att[j]; }
        const float inv = 1.f / (sqrtf(ss) + EPSV);
#pragma unroll
        for (int j = 0; j < 6; ++j) {
            qout[b * 6 + j]    = att[j] * inv;
            cellout[b * 6 + j] = cells[j];
        }
        const int a   = batch_a[b];
        const int pos = atomicAdd(&cnt[a], 1);
        rowlist[a * B + pos] = b;
    }
}

// ---------------- main: 8 rows/block, single pass over 10000 keys ----------------
__global__ __launch_bounds__(256) void main_kernel(
    const float* __restrict__ batch_x,
    const float* __restrict__ keys,      // [3,10000,6]
    const float* __restrict__ values,    // [3,10000,7]
    const int*   __restrict__ cnt,
    const int*   __restrict__ rowlist,
    const float* __restrict__ qin,
    const int*   __restrict__ cellin,
    float* __restrict__ out_x,
    float* __restrict__ out_unc,
    float* __restrict__ out_done,
    int B)
{
    const int a     = blockIdx.y;
    const int base  = blockIdx.x * MROWS;
    const int count = cnt[a];
    if (base >= count) return;
    const int tid = threadIdx.x;

    __shared__ int   s_row[MROWS];
    __shared__ float s_q[MROWS][6];
    __shared__ int   s_cell[MROWS][6];
    __shared__ float s_part[4][MROWS][9];   // 8 sums + max per wave
    __shared__ float s_delta[MROWS][6];

    if (tid < MROWS) {
        const int r   = tid;
        const int row = (base + r < count) ? rowlist[a * B + base + r] : -1;
        s_row[r] = row;
        if (row >= 0) {
#pragma unroll
            for (int j = 0; j < 6; ++j) {
                s_q[r][j]    = qin[row * 6 + j];
                s_cell[r][j] = cellin[row * 6 + j];
            }
        } else {
#pragma unroll
            for (int j = 0; j < 6; ++j) { s_q[r][j] = 0.f; s_cell[r][j] = 0; }
        }
    }
    __syncthreads();

    float q[MROWS][6];
#pragma unroll
    for (int r = 0; r < MROWS; ++r)
#pragma unroll
        for (int j = 0; j < 6; ++j) q[r][j] = s_q[r][j];

    const float* __restrict__ krow = keys   + (size_t)a * NKEYS * 6;
    const float* __restrict__ vrow = values + (size_t)a * NKEYS * 7;

    float acc[MROWS][8];
    float mx[MROWS];
#pragma unroll
    for (int r = 0; r < MROWS; ++r) {
        mx[r] = -INFINITY;
#pragma unroll
        for (int p = 0; p < 8; ++p) acc[r][p] = 0.f;
    }

    for (int n = tid; n < NKEYS; n += 256) {
        const float* kp = krow + n * 6;
        const float2 k01 = *(const float2*)(kp);
        const float2 k23 = *(const float2*)(kp + 2);
        const float2 k45 = *(const float2*)(kp + 4);
        const float nn = k01.x * k01.x + k01.y * k01.y + k23.x * k23.x +
                         k23.y * k23.y + k45.x * k45.x + k45.y * k45.y;
        const float invn = 1.f / (sqrtf(nn) + EPSV);
        const float* vp = vrow + n * 7;
        const float v0 = vp[0], v1 = vp[1], v2 = vp[2], v3 = vp[3],
                    v4 = vp[4], v5 = vp[5], v6 = vp[6];
#pragma unroll
        for (int r = 0; r < MROWS; ++r) {
            const float dot = q[r][0] * k01.x + q[r][1] * k01.y + q[r][2] * k23.x +
                              q[r][3] * k23.y + q[r][4] * k45.x + q[r][5] * k45.y;
            const float s = dot * invn;
            mx[r] = fmaxf(mx[r], s);
            const float e = __expf(s - 1.f);   // sim <= 1 always; softmax shift-invariant
            acc[r][0] += e;
            acc[r][1] += e * v0; acc[r][2] += e * v1; acc[r][3] += e * v2;
            acc[r][4] += e * v3; acc[r][5] += e * v4; acc[r][6] += e * v5;
            acc[r][7] += e * v6;
        }
    }

    // wave-level butterfly reduce, then cross-wave via LDS
#pragma unroll
    for (int r = 0; r < MROWS; ++r) {
#pragma unroll
        for (int p = 0; p < 8; ++p)
#pragma unroll
            for (int off = 32; off > 0; off >>= 1)
                acc[r][p] += __shfl_xor(acc[r][p], off);
#pragma unroll
        for (int off = 32; off > 0; off >>= 1)
            mx[r] = fmaxf(mx[r], __shfl_xor(mx[r], off));
    }
    const int wid = tid >> 6;
    if ((tid & 63) == 0) {
#pragma unroll
        for (int r = 0; r < MROWS; ++r) {
#pragma unroll
            for (int p = 0; p < 8; ++p) s_part[wid][r][p] = acc[r][p];
            s_part[wid][r][8] = mx[r];
        }
    }
    __syncthreads();

    if (tid < MROWS) {
        const int r   = tid;
        const int row = s_row[r];
        if (row >= 0) {
            float t[8];
#pragma unroll
            for (int p = 0; p < 8; ++p)
                t[p] = s_part[0][r][p] + s_part[1][r][p] + s_part[2][r][p] + s_part[3][r][p];
            const float mxf = fmaxf(fmaxf(s_part[0][r][8], s_part[1][r][8]),
                                    fmaxf(s_part[2][r][8], s_part[3][r][8]));
            const float inv = 1.f / t[0];
#pragma unroll
            for (int p = 0; p < 6; ++p) s_delta[r][p] = t[p + 1] * inv;
            out_unc[row]  = -mxf;
            out_done[row] = t[7] * inv;
        }
    }
    __syncthreads();

    // scatter deltas (ascending j -> last write wins) + copy rows
#pragma unroll
    for (int r = 0; r < MROWS; ++r) {
        const int row = s_row[r];
        if (row < 0) continue;   // uniform
        const int c0 = s_cell[r][0], c1 = s_cell[r][1], c2 = s_cell[r][2],
                  c3 = s_cell[r][3], c4 = s_cell[r][4], c5 = s_cell[r][5];
        const float d0 = s_delta[r][0], d1 = s_delta[r][1], d2 = s_delta[r][2],
                    d3 = s_delta[r][3], d4 = s_delta[r][4], d5 = s_delta[r][5];
        const float* xr  = batch_x + (size_t)row * GRID_D;
        float*       orr = out_x   + (size_t)row * GRID_D;
        for (int c = tid; c < GRID_D; c += 256) {
            float add = 0.f;
            if (c0 == c) add = d0;
            if (c1 == c) add = d1;
            if (c2 == c) add = d2;
            if (c3 == c) add = d3;
            if (c4 == c) add = d4;
            if (c5 == c) add = d5;
            orr[c] = xr[c] + add;
        }
    }
}

extern "C" void kernel_launch(void* const* d_in, const int* in_sizes, int n_in,
                              void* d_out, int out_size, void* d_ws, size_t ws_size,
                              hipStream_t stream) {
    const float* batch_x = (const float*)d_in[0];
    const int*   batch_a = (const int*)d_in[1];
    const float* keys    = (const float*)d_in[2];
    const float* values  = (const float*)d_in[3];
    const int B = in_sizes[1];                 // 4096

    float* out      = (float*)d_out;
    float* out_x    = out;
    float* out_unc  = out + (size_t)B * GRID_D;
    float* out_done = out_unc + B;

    // workspace layout
    int*   cnt     = (int*)d_ws;               // 4 ints
    int*   rowlist = cnt + 4;                  // 3*B ints
    float* qbuf    = (float*)(rowlist + 3 * B);// B*6 floats
    int*   cellbuf = (int*)(qbuf + (size_t)B * 6); // B*6 ints

    hipMemsetAsync(cnt, 0, 4 * sizeof(int), stream);

    prep_kernel<<<B, 64, 0, stream>>>(batch_x, batch_a, cnt, rowlist, qbuf, cellbuf, B);

    const int chunks = (B + MROWS - 1) / MROWS;
    main_kernel<<<dim3(chunks, 3), 256, 0, stream>>>(
        batch_x, keys, values, cnt, rowlist, qbuf, cellbuf,
        out_x, out_unc, out_done, B);
}

// Round 3
// 118.438 us; speedup vs baseline: 1.0999x; 1.0999x over previous
//
#include <hip/hip_runtime.h>
#include <math.h>

#define GRID_D 362
#define NKEYS  10000
#define EPSV   1e-8f
#define MROWS  8

__device__ __forceinline__ float rfl(float x) {
    return __int_as_float(__builtin_amdgcn_readfirstlane(__float_as_int(x)));
}

// ---------- prep: 4 rows/block (1 wave each): argmax -> q, cells; bucket by a ----------
__global__ __launch_bounds__(256) void prep_kernel(
    const float* __restrict__ batch_x,
    const int*   __restrict__ batch_a,
    int*   __restrict__ cnt,        // [4] zeroed
    int*   __restrict__ rowlist,    // [3*B]
    float* __restrict__ qout,       // [B*6]
    int*   __restrict__ cellout,    // [B*6]
    int B)
{
    const int wid  = threadIdx.x >> 6;
    const int lane = threadIdx.x & 63;
    const int b    = blockIdx.x * 4 + wid;
    if (b >= B) return;
    const float* x = batch_x + (size_t)b * GRID_D;

    float bestv = -INFINITY;
    int   besti = 1 << 30;
    for (int i = lane; i < GRID_D; i += 64) {
        float v = x[i];
        if (v > bestv || (v == bestv && i < besti)) { bestv = v; besti = i; }
    }
#pragma unroll
    for (int off = 32; off > 0; off >>= 1) {
        float ov = __shfl_down(bestv, off);
        int   oi = __shfl_down(besti, off);
        if (ov > bestv || (ov == bestv && oi < besti)) { bestv = ov; besti = oi; }
    }
    if (lane == 0) {
        const int ptr = besti;
        int cells[6];
        cells[0] = 0;
        cells[1] = ptr;
        cells[2] = min(max(ptr - 19, 1), GRID_D - 1);
        cells[3] = min(max(ptr + 19, 1), GRID_D - 1);
        cells[4] = min(max(ptr - 1,  1), GRID_D - 1);
        cells[5] = min(max(ptr + 1,  1), GRID_D - 1);
        float att[6], ss = 0.f;
#pragma unroll
        for (int j = 0; j < 6; ++j) { att[j] = x[cells[j]]; ss += att[j] * att[j]; }
        const float inv = 1.f / (sqrtf(ss) + EPSV);
#pragma unroll
        for (int j = 0; j < 6; ++j) {
            qout[b * 6 + j]    = att[j] * inv;
            cellout[b * 6 + j] = cells[j];
        }
        const int a   = batch_a[b];
        const int pos = atomicAdd(&cnt[a], 1);
        rowlist[a * B + pos] = b;
    }
}

// ---------- main: 8 rows/block, key-slice per blockIdx.z, partials to ws ----------
__global__ __launch_bounds__(256) void main_kernel(
    const float* __restrict__ keys,      // [3,10000,6]
    const float* __restrict__ values,    // [3,10000,7]
    const int*   __restrict__ cnt,
    const int*   __restrict__ rowlist,
    const float* __restrict__ qin,
    float* __restrict__ partial,         // [ksplit][B][9]
    int B, int kps)
{
    const int a     = blockIdx.y;
    const int base  = blockIdx.x * MROWS;
    const int count = cnt[a];
    if (base >= count) return;
    const int tid = threadIdx.x;
    const int ks  = blockIdx.z;

    __shared__ int   s_row[MROWS];
    __shared__ float s_q[MROWS][6];
    __shared__ float s_part[4][MROWS][9];

    if (tid < MROWS)
        s_row[tid] = (base + tid < count) ? rowlist[a * B + base + tid] : -1;
    if (tid < MROWS * 6) {
        const int r = tid / 6, j = tid % 6;
        const int row = (base + r < count) ? rowlist[a * B + base + r] : -1;
        s_q[r][j] = (row >= 0) ? qin[row * 6 + j] : 0.f;
    }
    __syncthreads();

    // wave-uniform query coefficients -> SGPRs
    float qs[MROWS][6];
#pragma unroll
    for (int r = 0; r < MROWS; ++r)
#pragma unroll
        for (int j = 0; j < 6; ++j) qs[r][j] = rfl(s_q[r][j]);

    const float* __restrict__ krow = keys   + (size_t)a * NKEYS * 6;
    const float* __restrict__ vrow = values + (size_t)a * NKEYS * 7;
    const int n0 = ks * kps;
    const int n1 = min(n0 + kps, NKEYS);

    float acc[MROWS][8];
    float mx[MROWS];
#pragma unroll
    for (int r = 0; r < MROWS; ++r) {
        mx[r] = -INFINITY;
#pragma unroll
        for (int p = 0; p < 8; ++p) acc[r][p] = 0.f;
    }

    // unroll-2: two independent load->compute chains per iteration
    for (int n = n0 + tid; n < n1; n += 512) {
        const int n2 = n + 256;
        const bool has2 = (n2 < n1);

        const float* kp = krow + n * 6;
        const float2 ka0 = *(const float2*)(kp);
        const float2 ka1 = *(const float2*)(kp + 2);
        const float2 ka2 = *(const float2*)(kp + 4);
        const float* vp = vrow + n * 7;
        const float va0 = vp[0], va1 = vp[1], va2 = vp[2], va3 = vp[3],
                    va4 = vp[4], va5 = vp[5], va6 = vp[6];

        float2 kb0, kb1, kb2;
        float vb0 = 0, vb1 = 0, vb2 = 0, vb3 = 0, vb4 = 0, vb5 = 0, vb6 = 0;
        kb0 = kb1 = kb2 = make_float2(0.f, 0.f);
        if (has2) {
            const float* kp2 = krow + n2 * 6;
            kb0 = *(const float2*)(kp2);
            kb1 = *(const float2*)(kp2 + 2);
            kb2 = *(const float2*)(kp2 + 4);
            const float* vp2 = vrow + n2 * 7;
            vb0 = vp2[0]; vb1 = vp2[1]; vb2 = vp2[2]; vb3 = vp2[3];
            vb4 = vp2[4]; vb5 = vp2[5]; vb6 = vp2[6];
        }

        {
            const float nn = ka0.x*ka0.x + ka0.y*ka0.y + ka1.x*ka1.x +
                             ka1.y*ka1.y + ka2.x*ka2.x + ka2.y*ka2.y;
            const float invn = 1.f / (sqrtf(nn) + EPSV);
#pragma unroll
            for (int r = 0; r < MROWS; ++r) {
                const float dot = qs[r][0]*ka0.x + qs[r][1]*ka0.y + qs[r][2]*ka1.x +
                                  qs[r][3]*ka1.y + qs[r][4]*ka2.x + qs[r][5]*ka2.y;
                const float s = dot * invn;
                mx[r] = fmaxf(mx[r], s);
                const float e = __expf(s - 1.f);   // sim<=1; softmax shift-invariant
                acc[r][0] += e;
                acc[r][1] += e*va0; acc[r][2] += e*va1; acc[r][3] += e*va2;
                acc[r][4] += e*va3; acc[r][5] += e*va4; acc[r][6] += e*va5;
                acc[r][7] += e*va6;
            }
        }
        if (has2) {
            const float nn = kb0.x*kb0.x + kb0.y*kb0.y + kb1.x*kb1.x +
                             kb1.y*kb1.y + kb2.x*kb2.x + kb2.y*kb2.y;
            const float invn = 1.f / (sqrtf(nn) + EPSV);
#pragma unroll
            for (int r = 0; r < MROWS; ++r) {
                const float dot = qs[r][0]*kb0.x + qs[r][1]*kb0.y + qs[r][2]*kb1.x +
                                  qs[r][3]*kb1.y + qs[r][4]*kb2.x + qs[r][5]*kb2.y;
                const float s = dot * invn;
                mx[r] = fmaxf(mx[r], s);
                const float e = __expf(s - 1.f);
                acc[r][0] += e;
                acc[r][1] += e*vb0; acc[r][2] += e*vb1; acc[r][3] += e*vb2;
                acc[r][4] += e*vb3; acc[r][5] += e*vb4; acc[r][6] += e*vb5;
                acc[r][7] += e*vb6;
            }
        }
    }

    // wave butterfly reduce, then cross-wave combine + partial write
#pragma unroll
    for (int r = 0; r < MROWS; ++r) {
#pragma unroll
        for (int p = 0; p < 8; ++p)
#pragma unroll
            for (int off = 32; off > 0; off >>= 1)
                acc[r][p] += __shfl_xor(acc[r][p], off);
#pragma unroll
        for (int off = 32; off > 0; off >>= 1)
            mx[r] = fmaxf(mx[r], __shfl_xor(mx[r], off));
    }
    const int w = tid >> 6;
    if ((tid & 63) == 0) {
#pragma unroll
        for (int r = 0; r < MROWS; ++r) {
#pragma unroll
            for (int p = 0; p < 8; ++p) s_part[w][r][p] = acc[r][p];
            s_part[w][r][8] = mx[r];
        }
    }
    __syncthreads();

    if (tid < MROWS * 9) {
        const int r = tid / 9, p = tid % 9;
        const int row = s_row[r];
        if (row >= 0) {
            float v;
            if (p < 8)
                v = s_part[0][r][p] + s_part[1][r][p] + s_part[2][r][p] + s_part[3][r][p];
            else
                v = fmaxf(fmaxf(s_part[0][r][8], s_part[1][r][8]),
                          fmaxf(s_part[2][r][8], s_part[3][r][8]));
            partial[((size_t)blockIdx.z * B + row) * 9 + p] = v;
        }
    }
}

// ---------- finalize: combine splits, write outputs ----------
__global__ __launch_bounds__(64) void final_kernel(
    const float* __restrict__ batch_x,
    const float* __restrict__ partial,   // [ksplit][B][9]
    const int*   __restrict__ cellin,
    float* __restrict__ out_x,
    float* __restrict__ out_unc,
    float* __restrict__ out_done,
    int B, int ksplit)
{
    const int b    = blockIdx.x;
    const int lane = threadIdx.x;
    __shared__ float s_t[9];
    __shared__ float s_d[6];
    __shared__ int   s_c[6];

    if (lane < 9) {
        float v = partial[(size_t)b * 9 + lane];
        for (int s = 1; s < ksplit; ++s) {
            const float u = partial[((size_t)s * B + b) * 9 + lane];
            v = (lane == 8) ? fmaxf(v, u) : (v + u);
        }
        s_t[lane] = v;
    }
    if (lane < 6) s_c[lane] = cellin[b * 6 + lane];
    __syncthreads();
    if (lane < 8) {
        const float inv = 1.f / s_t[0];
        if (lane < 6) s_d[lane] = s_t[lane + 1] * inv;
        if (lane == 6) out_done[b] = s_t[7] * inv;
        if (lane == 7) out_unc[b]  = -s_t[8];
    }
    __syncthreads();

    const int   c0 = s_c[0], c1 = s_c[1], c2 = s_c[2],
                c3 = s_c[3], c4 = s_c[4], c5 = s_c[5];
    const float d0 = s_d[0], d1 = s_d[1], d2 = s_d[2],
                d3 = s_d[3], d4 = s_d[4], d5 = s_d[5];
    const float* x = batch_x + (size_t)b * GRID_D;
    float*       o = out_x   + (size_t)b * GRID_D;
    for (int c = lane; c < GRID_D; c += 64) {
        float add = 0.f;
        if (c0 == c) add = d0;
        if (c1 == c) add = d1;
        if (c2 == c) add = d2;
        if (c3 == c) add = d3;
        if (c4 == c) add = d4;
        if (c5 == c) add = d5;     // ascending j -> last write wins
        o[c] = x[c] + add;
    }
}

extern "C" void kernel_launch(void* const* d_in, const int* in_sizes, int n_in,
                              void* d_out, int out_size, void* d_ws, size_t ws_size,
                              hipStream_t stream) {
    const float* batch_x = (const float*)d_in[0];
    const int*   batch_a = (const int*)d_in[1];
    const float* keys    = (const float*)d_in[2];
    const float* values  = (const float*)d_in[3];
    const int B = in_sizes[1];                 // 4096

    float* out      = (float*)d_out;
    float* out_x    = out;
    float* out_unc  = out + (size_t)B * GRID_D;
    float* out_done = out_unc + B;

    // workspace layout
    int*   cnt     = (int*)d_ws;                       // 4 ints
    int*   rowlist = cnt + 4;                          // 3*B ints
    float* qbuf    = (float*)(rowlist + 3 * B);        // B*6 floats
    int*   cellbuf = (int*)(qbuf + (size_t)B * 6);     // B*6 ints
    float* partial = (float*)(cellbuf + (size_t)B * 6);// ksplit*B*9 floats

    const size_t fixed_bytes = ((size_t)4 + 3 * B + 6 * B + 6 * B) * 4;
    int ksplit = 2;
    if (ws_size < fixed_bytes + (size_t)ksplit * B * 9 * 4) ksplit = 1;

    hipMemsetAsync(cnt, 0, 4 * sizeof(int), stream);

    prep_kernel<<<dim3((B + 3) / 4), 256, 0, stream>>>(
        batch_x, batch_a, cnt, rowlist, qbuf, cellbuf, B);

    const int kps = (NKEYS + ksplit - 1) / ksplit;
    main_kernel<<<dim3((B + MROWS - 1) / MROWS, 3, ksplit), 256, 0, stream>>>(
        keys, values, cnt, rowlist, qbuf, partial, B, kps);

    final_kernel<<<B, 64, 0, stream>>>(
        batch_x, partial, cellbuf, out_x, out_unc, out_done, B, ksplit);
}